// Round 10
// baseline (275.707 us; speedup 1.0000x reference)
//
#include <hip/hip_runtime.h>

// HybridLoss: 0.8*MSE + 0.2*(1-SSIM), SSIM via separable 11x11 Gaussian (sigma=1.5)
// Input: pred, target f32 (32,3,512,512). Output: scalar f32.
// Streaming strip (64 wide x 128 tall), 256-thread blocks, BUF=42 circular LDS
// float4 plane: (mu_x, mu_y, E[x^2+y^2], E[xy]).
// SINGLE barrier per 16-row chunk: hconv of chunk k+26..k+41 writes slots that are
// provably disjoint (mod 42) from vconv k's read window 16k..16k+25, so both run
// in one phase; global-load latency hides under vconv IN THE SAME BASIC BLOCK
// (r9 lesson: compiler refuses to keep prefetch regs live ACROSS a barrier).
// __launch_bounds__ min-waves stays 4: 6 clamped VGPR to 40 and spilled (r5/r7).

#define W 512
#define H 512
#define NIMG 96
#define TX 64
#define CHUNK 16
#define STRIP 128
#define NITER 8            // STRIP/CHUNK
#define BUF 42             // window 26 + chunk 16 -> same-phase write/read disjoint
#define PAD4 65            // float4 row stride: 1040 B == 16 mod 128 -> uniform banks
#define NSLOT 128

// symmetric gaussian: gw[k] == gwu[k<6 ? k : 10-k], k compile-time in unrolled loops
#define GW(k) gwu[(k) < 6 ? (k) : 10 - (k)]

__global__ void hybrid_init(double* __restrict__ ws) {
    int t = threadIdx.x;
    if (t < 2 * NSLOT) ws[t] = 0.0;
}

__global__ __launch_bounds__(256, 4) void hybrid_main(
    const float* __restrict__ pred, const float* __restrict__ targ,
    double* __restrict__ ws)
{
    __shared__ float4 s_q[BUF][PAD4];   // 42*1040 = 43680 B -> 3 blocks/CU

    const int tid = threadIdx.x;
    const float* __restrict__ pp = pred + (size_t)blockIdx.z * (H * W);
    const float* __restrict__ tp = targ + (size_t)blockIdx.z * (H * W);
    const int xbase = blockIdx.x * TX;
    const int Y0 = blockIdx.y * STRIP;

    // Normalized 1D Gaussian, 6 unique weights (symmetric), f32 like ref
    float gwu[6];
    {
        float s = 0.f;
#pragma unroll
        for (int k = 0; k < 6; ++k) {
            float d = (float)(k - 5);
            gwu[k] = expf(-d * d / 4.5f);   // 2*sigma^2 = 4.5
            s += (k < 5) ? 2.f * gwu[k] : gwu[k];
        }
        float inv = 1.f / s;
#pragma unroll
        for (int k = 0; k < 6; ++k) gwu[k] *= inv;
    }

    const int hrow_i = tid >> 4;       // 0..15 : hconv row-in-chunk
    const int g      = tid & 15;       // 4-col group
    const int c0     = g * 4;
    const int A0     = xbase + c0 - 8; // aligned 20-px window [A0, A0+20)
    const bool inX   = (A0 >= 0) && (A0 + 20 <= W);

    const int wv = tid >> 6;           // wave 0..3 (vconv 4-row runs)
    const int cc = tid & 63;           // output column within tile

    float mse_local = 0.f, ssim_local = 0.f;
    float pxa[20], pya[20];            // staging registers (one image row)

    // Load image row gy into pxa/pya (zeros outside image).
    auto load_row = [&](int gy) {
        if (gy >= 0 && gy < H) {
            const float* __restrict__ px = pp + (size_t)gy * W;
            const float* __restrict__ py = tp + (size_t)gy * W;
            if (inX) {
                const float4* qx = (const float4*)(px + A0);
                const float4* qy = (const float4*)(py + A0);
#pragma unroll
                for (int v = 0; v < 5; ++v) {
                    float4 a = qx[v], b = qy[v];
                    pxa[4*v+0]=a.x; pxa[4*v+1]=a.y; pxa[4*v+2]=a.z; pxa[4*v+3]=a.w;
                    pya[4*v+0]=b.x; pya[4*v+1]=b.y; pya[4*v+2]=b.z; pya[4*v+3]=b.w;
                }
            } else {
#pragma unroll
                for (int j = 0; j < 20; ++j) {
                    int col = A0 + j;
                    bool ok = (col >= 0) && (col < W);
                    pxa[j] = ok ? px[col] : 0.f;
                    pya[j] = ok ? py[col] : 0.f;
                }
            }
        } else {
#pragma unroll
            for (int j = 0; j < 20; ++j) { pxa[j] = 0.f; pya[j] = 0.f; }
        }
    };

    // Consume pxa/pya: MSE (raw) + clip + horizontal 11-tap of 4 quantities -> LDS.
    auto hconv_store = [&](int slot, bool own) {
        if (own) {
#pragma unroll
            for (int c = 0; c < 4; ++c) {
                float d = pxa[8 + c] - pya[8 + c];
                mse_local = fmaf(d, d, mse_local);
            }
        }
        float a0[4]={0,0,0,0}, a1[4]={0,0,0,0}, a2[4]={0,0,0,0}, a3[4]={0,0,0,0};
#pragma unroll
        for (int j = 0; j < 14; ++j) {        // window positions 3..16
            float cx = __builtin_amdgcn_fmed3f(pxa[3 + j], 0.f, 1.f);
            float yv = pya[3 + j];
            float s2 = fmaf(yv, yv, cx * cx); // x^2 + y^2
            float xy = cx * yv;
#pragma unroll
            for (int i = 0; i < 4; ++i) {
                int k = j - i;
                if (k >= 0 && k < 11) {
                    float w = GW(k);
                    a0[i] = fmaf(w, cx, a0[i]);
                    a1[i] = fmaf(w, yv, a1[i]);
                    a2[i] = fmaf(w, s2, a2[i]);
                    a3[i] = fmaf(w, xy, a3[i]);
                }
            }
        }
#pragma unroll
        for (int i = 0; i < 4; ++i)
            s_q[slot][c0 + i] = make_float4(a0[i], a1[i], a2[i], a3[i]);
    };

    // Prologue: ext rows 0..25 -> slots 0..25 (owned = ext in [5,132])
    load_row(Y0 - 5 + hrow_i);
    hconv_store(hrow_i, hrow_i >= 5);
    if (hrow_i < 10) {
        load_row(Y0 + 11 + hrow_i);           // ext 16..25
        hconv_store(16 + hrow_i, true);
    }
    __syncthreads();

    const float C1 = 1e-4f, C2 = 9e-4f;

#pragma unroll
    for (int k = 0; k < NITER; ++k) {
        // ---- issue chunk-(k) hconv loads first: ext rows 16k+26 .. 16k+41 ----
        const int exth = CHUNK * k + 26 + hrow_i;        // 26..153
        const bool do_h = (exth <= STRIP + 9);           // valid ext rows <= 137
        if (do_h) load_row(Y0 - 5 + exth);

        // ---- vconv k (reads ext 16k .. 16k+25); loads in flight above ----
        {
            const int vb = (CHUNK * k) % BUF;            // compile-time
            int t0 = vb + 4 * wv; if (t0 >= BUF) t0 -= BUF;
            float ax[4]={0,0,0,0}, ay[4]={0,0,0,0};
            float as[4]={0,0,0,0}, axy[4]={0,0,0,0};
#pragma unroll
            for (int j = 0; j < 14; ++j) {
                int s = t0 + j; if (s >= BUF) s -= BUF;
                float4 q = s_q[s][cc];
#pragma unroll
                for (int i = 0; i < 4; ++i) {
                    int kk = j - i;
                    if (kk >= 0 && kk < 11) {
                        float w = GW(kk);
                        ax [i] = fmaf(w, q.x, ax [i]);
                        ay [i] = fmaf(w, q.y, ay [i]);
                        as [i] = fmaf(w, q.z, as [i]);
                        axy[i] = fmaf(w, q.w, axy[i]);
                    }
                }
            }
#pragma unroll
            for (int i = 0; i < 4; ++i) {
                float mu_x2 = ax[i]*ax[i], mu_y2 = ay[i]*ay[i], mu_xy = ax[i]*ay[i];
                float ssum = as[i] - mu_x2 - mu_y2;      // sigma_x2 + sigma_y2
                float sxy  = axy[i] - mu_xy;
                float num = (2.f*mu_xy + C1) * (2.f*sxy + C2);
                float den = (mu_x2 + mu_y2 + C1) * (ssum + C2);
                ssim_local = fmaf(num, __builtin_amdgcn_rcpf(den), ssim_local);
            }
        }

        // ---- hconv consume+store: slots disjoint (mod 42) from vconv reads ----
        if (do_h) {
            const int hs = (CHUNK * k + 26) % BUF;       // compile-time
            int slot = hs + hrow_i; if (slot >= BUF) slot -= BUF;
            hconv_store(slot, exth <= STRIP + 4);
        }
        __syncthreads();   // single barrier per chunk
    }

    // ---- Per-wave reduction + spread f64 atomics ----
    float m = mse_local, s2 = ssim_local;
#pragma unroll
    for (int off = 32; off; off >>= 1) {
        m  += __shfl_down(m, off);
        s2 += __shfl_down(s2, off);
    }
    if ((tid & 63) == 0) {
        int flat = blockIdx.x + 8 * (blockIdx.y + 4 * blockIdx.z);
        int slot = (flat * 4 + wv) & (NSLOT - 1);
        atomicAdd(&ws[slot], (double)m);
        atomicAdd(&ws[NSLOT + slot], (double)s2);
    }
}

__global__ void hybrid_fin(const double* __restrict__ ws, float* __restrict__ out) {
    int t = threadIdx.x;  // 64 threads
    double m = ws[t] + ws[t + 64];
    double s = ws[NSLOT + t] + ws[NSLOT + t + 64];
#pragma unroll
    for (int off = 32; off; off >>= 1) {
        m += __shfl_down(m, off);
        s += __shfl_down(s, off);
    }
    if (t == 0) {
        const double N = (double)NIMG * H * W;
        double mse  = m / N;
        double ssim = s / N;
        out[0] = (float)(0.8 * mse + 0.2 * (1.0 - ssim));
    }
}

extern "C" void kernel_launch(void* const* d_in, const int* in_sizes, int n_in,
                              void* d_out, int out_size, void* d_ws, size_t ws_size,
                              hipStream_t stream) {
    const float* pred = (const float*)d_in[0];
    const float* targ = (const float*)d_in[1];
    double* ws = (double*)d_ws;
    float* out = (float*)d_out;

    hybrid_init<<<1, 256, 0, stream>>>(ws);
    dim3 grid(W / TX, H / STRIP, NIMG);
    hybrid_main<<<grid, dim3(256), 0, stream>>>(pred, targ, ws);
    hybrid_fin<<<1, 64, 0, stream>>>(ws, out);
}

// Round 11
// 108.801 us; speedup vs baseline: 2.5340x; 2.5340x over previous
//
#include <hip/hip_runtime.h>

// HybridLoss: 0.8*MSE + 0.2*(1-SSIM), SSIM via separable 11x11 Gaussian (sigma=1.5)
// Input: pred, target f32 (32,3,512,512). Output: scalar f32.
// r6 geometry (64x128 strip, 256 thr, CHUNK=16, BUF=26, 2 barriers/chunk) +
// ASYNC RAW-PIXEL STAGING via global_load_lds (zero VGPR cost — r9/r10 showed
// register prefetch either gets sunk by the compiler or blows VGPR to 148):
//   hconv k (reads s_raw) | barrier A | DMA chunk k+1 -> s_raw ; vconv k |
//   barrier B (vmcnt drain -> s_raw = chunk k+1).
// Single raw buffer: reads and DMA writes are barrier-separated. 36.4 KB LDS
// -> 4 blocks/CU. __launch_bounds__ min-waves stays 4 (6 clamps VGPR->40, spills).

#define W 512
#define H 512
#define NIMG 96
#define TX 64
#define CHUNK 16
#define STRIP 128
#define NITER 8            // STRIP/CHUNK
#define BUF 26             // s_q circular rows
#define PAD4 65            // float4 row stride: 1040 B -> uniform bank spread
#define NSLOT 128
#define RAWB 10240         // raw staging: 2 tensors * 16 rows * 320 B

// symmetric gaussian: gw[k] == gwu[k<6 ? k : 10-k], k compile-time when unrolled
#define GW(k) gwu[(k) < 6 ? (k) : 10 - (k)]

__global__ void hybrid_init(double* __restrict__ ws) {
    int t = threadIdx.x;
    if (t < 2 * NSLOT) ws[t] = 0.0;
}

__global__ __launch_bounds__(256, 4) void hybrid_main(
    const float* __restrict__ pred, const float* __restrict__ targ,
    double* __restrict__ ws)
{
    __shared__ float4 s_q[BUF][PAD4];             // 27040 B: hconv results
    __shared__ __align__(16) char s_raw[RAWB];    // 10240 B: staged raw pixels

    const int tid = threadIdx.x;
    const float* __restrict__ pp = pred + (size_t)blockIdx.z * (H * W);
    const float* __restrict__ tp = targ + (size_t)blockIdx.z * (H * W);
    const int xbase = blockIdx.x * TX;
    const int Y0 = blockIdx.y * STRIP;
    const int xb8 = xbase - 8;         // raw window = [xb8, xb8+80)

    // Normalized 1D Gaussian, 6 unique weights (symmetric), f32 like ref
    float gwu[6];
    {
        float s = 0.f;
#pragma unroll
        for (int k = 0; k < 6; ++k) {
            float d = (float)(k - 5);
            gwu[k] = expf(-d * d / 4.5f);   // 2*sigma^2 = 4.5
            s += (k < 5) ? 2.f * gwu[k] : gwu[k];
        }
        float inv = 1.f / s;
#pragma unroll
        for (int k = 0; k < 6; ++k) gwu[k] *= inv;
    }

    const int hrow_i = tid >> 4;       // 0..15 : hconv row-in-chunk
    const int g      = tid & 15;       // 4-col group
    const int c0     = g * 4;
    const int A0     = xbase + c0 - 8; // 20-px window [A0, A0+20)
    const bool inX   = (A0 >= 0) && (A0 + 20 <= W);

    const int wv     = tid >> 6;       // wave 0..3
    const int cc     = tid & 63;       // vconv column
    const int lane16 = (tid & 63) * 16;

    float mse_local = 0.f, ssim_local = 0.f;

    // ---- async DMA one 16-row chunk (ext rows 16kc+10..+25) into s_raw ----
    // 10 wave-chunks of 1024 B; LDS dest = uniform base + lane*16 (HW rule);
    // per-lane global source with gy/col clamped (OOB fixed by masks at consume).
    auto issue_chunk = [&](int kc) {
        const int gybase = Y0 + 5 + CHUNK * kc;
#pragma unroll
        for (int m0 = 0; m0 < 12; m0 += 4) {
            const int m = wv + m0;                    // wave-uniform
            if (m < 10) {
                const int t  = (m >= 5);
                const int oo = (m - 5 * t) * 1024 + lane16;  // byte in tensor
                const int r  = oo / 320;
                const int cb = oo - r * 320;
                int gy = gybase + r; if (gy > H - 1) gy = H - 1;
                int col = xb8 + (cb >> 2);
                col = col < 0 ? 0 : (col > W - 4 ? W - 4 : col);
                const float* src = (t ? tp : pp) + gy * W + col;
                const char* dst = s_raw + m * 1024;          // uniform base
                __builtin_amdgcn_global_load_lds(
                    (const __attribute__((address_space(1))) void*)src,
                    (__attribute__((address_space(3))) void*)dst, 16, 0, 0);
            }
        }
    };

    // ---- read this thread's 20-px window from s_raw (+ x-edge masks) ----
    auto read_staged = [&](float* xa, float* ya) {
#pragma unroll
        for (int v = 0; v < 5; ++v) {
            const int off = hrow_i * 320 + (g + v) * 16;
            float4 a = *(const float4*)&s_raw[off];
            float4 b = *(const float4*)&s_raw[RAWB / 2 + off];
            xa[4*v+0]=a.x; xa[4*v+1]=a.y; xa[4*v+2]=a.z; xa[4*v+3]=a.w;
            ya[4*v+0]=b.x; ya[4*v+1]=b.y; ya[4*v+2]=b.z; ya[4*v+3]=b.w;
        }
        if (!inX) {                      // only blocks x=0,7 ever diverge here
#pragma unroll
            for (int j = 0; j < 20; ++j) {
                if ((unsigned)(A0 + j) >= (unsigned)W) { xa[j] = 0.f; ya[j] = 0.f; }
            }
        }
    };

    // ---- MSE (raw) + clip + horizontal 11-tap of 4 quantities -> s_q ----
    auto hconv_store = [&](const float* xa, const float* ya, int slot, bool own) {
        if (own) {
#pragma unroll
            for (int c = 0; c < 4; ++c) {
                float d = xa[8 + c] - ya[8 + c];
                mse_local = fmaf(d, d, mse_local);
            }
        }
        float a0[4]={0,0,0,0}, a1[4]={0,0,0,0}, a2[4]={0,0,0,0}, a3[4]={0,0,0,0};
#pragma unroll
        for (int j = 0; j < 14; ++j) {        // window positions 3..16
            float cx = __builtin_amdgcn_fmed3f(xa[3 + j], 0.f, 1.f);
            float yv = ya[3 + j];
            float s2 = fmaf(yv, yv, cx * cx); // x^2 + y^2
            float xy = cx * yv;
#pragma unroll
            for (int i = 0; i < 4; ++i) {
                int k = j - i;
                if (k >= 0 && k < 11) {
                    float w = GW(k);
                    a0[i] = fmaf(w, cx, a0[i]);
                    a1[i] = fmaf(w, yv, a1[i]);
                    a2[i] = fmaf(w, s2, a2[i]);
                    a3[i] = fmaf(w, xy, a3[i]);
                }
            }
        }
#pragma unroll
        for (int i = 0; i < 4; ++i)
            s_q[slot][c0 + i] = make_float4(a0[i], a1[i], a2[i], a3[i]);
    };

    // ---- Prologue: DMA chunk 0; direct-load hconv of ext rows 0..9 ----
    issue_chunk(0);
    if (hrow_i < 10) {
        float xa[20], ya[20];
        const int gy = Y0 - 5 + hrow_i;
        if (gy >= 0 && gy < H) {
            const float* __restrict__ px = pp + (size_t)gy * W;
            const float* __restrict__ py = tp + (size_t)gy * W;
            if (inX) {
                const float4* qx = (const float4*)(px + A0);
                const float4* qy = (const float4*)(py + A0);
#pragma unroll
                for (int v = 0; v < 5; ++v) {
                    float4 a = qx[v], b = qy[v];
                    xa[4*v+0]=a.x; xa[4*v+1]=a.y; xa[4*v+2]=a.z; xa[4*v+3]=a.w;
                    ya[4*v+0]=b.x; ya[4*v+1]=b.y; ya[4*v+2]=b.z; ya[4*v+3]=b.w;
                }
            } else {
#pragma unroll
                for (int j = 0; j < 20; ++j) {
                    int col = A0 + j;
                    bool ok = (col >= 0) && (col < W);
                    xa[j] = ok ? px[col] : 0.f;
                    ya[j] = ok ? py[col] : 0.f;
                }
            }
        } else {
#pragma unroll
            for (int j = 0; j < 20; ++j) { xa[j] = 0.f; ya[j] = 0.f; }
        }
        hconv_store(xa, ya, hrow_i, hrow_i >= 5);
    }
    __syncthreads();   // drains chunk-0 DMA; prologue s_q visible

    const float C1 = 1e-4f, C2 = 9e-4f;

#pragma unroll
    for (int k = 0; k < NITER; ++k) {
        // ---- hconv k from staged s_raw: ext rows 16k+10 .. 16k+25 ----
        {
            const int ext = CHUNK * k + 10 + hrow_i;
            const int gy  = Y0 - 5 + ext;                // >= 5, can exceed H-1
            const int hb  = (10 + CHUNK * k) % BUF;      // compile-time
            int slot = hb + hrow_i; if (slot >= BUF) slot -= BUF;
            float xa[20], ya[20];
            if (gy < H) {
                read_staged(xa, ya);
            } else {
#pragma unroll
                for (int j = 0; j < 20; ++j) { xa[j] = 0.f; ya[j] = 0.f; }
            }
            hconv_store(xa, ya, slot, ext <= STRIP + 4);
        }
        __syncthreads();   // A: s_q visible; all s_raw reads complete

        // ---- DMA next chunk into s_raw; latency hides under vconv ----
        if (k + 1 < NITER) issue_chunk(k + 1);

        // ---- vconv k (reads s_q ext 16k .. 16k+25) ----
        {
            const int vb = (CHUNK * k) % BUF;            // compile-time
            int t0 = vb + 4 * wv; if (t0 >= BUF) t0 -= BUF;
            float ax[4]={0,0,0,0}, ay[4]={0,0,0,0};
            float as[4]={0,0,0,0}, axy[4]={0,0,0,0};
#pragma unroll
            for (int j = 0; j < 14; ++j) {
                int s = t0 + j; if (s >= BUF) s -= BUF;
                float4 q = s_q[s][cc];
#pragma unroll
                for (int i = 0; i < 4; ++i) {
                    int kk = j - i;
                    if (kk >= 0 && kk < 11) {
                        float w = GW(kk);
                        ax [i] = fmaf(w, q.x, ax [i]);
                        ay [i] = fmaf(w, q.y, ay [i]);
                        as [i] = fmaf(w, q.z, as [i]);
                        axy[i] = fmaf(w, q.w, axy[i]);
                    }
                }
            }
#pragma unroll
            for (int i = 0; i < 4; ++i) {
                float mu_x2 = ax[i]*ax[i], mu_y2 = ay[i]*ay[i], mu_xy = ax[i]*ay[i];
                float ssum = as[i] - mu_x2 - mu_y2;      // sigma_x2 + sigma_y2
                float sxy  = axy[i] - mu_xy;
                float num = (2.f*mu_xy + C1) * (2.f*sxy + C2);
                float den = (mu_x2 + mu_y2 + C1) * (ssum + C2);
                ssim_local = fmaf(num, __builtin_amdgcn_rcpf(den), ssim_local);
            }
        }
        __syncthreads();   // B: drains DMA (s_raw = chunk k+1); s_q reads done
    }

    // ---- Per-wave reduction + spread f64 atomics ----
    float m = mse_local, s2 = ssim_local;
#pragma unroll
    for (int off = 32; off; off >>= 1) {
        m  += __shfl_down(m, off);
        s2 += __shfl_down(s2, off);
    }
    if ((tid & 63) == 0) {
        int flat = blockIdx.x + 8 * (blockIdx.y + 4 * blockIdx.z);
        int slot = (flat * 4 + wv) & (NSLOT - 1);
        atomicAdd(&ws[slot], (double)m);
        atomicAdd(&ws[NSLOT + slot], (double)s2);
    }
}

__global__ void hybrid_fin(const double* __restrict__ ws, float* __restrict__ out) {
    int t = threadIdx.x;  // 64 threads
    double m = ws[t] + ws[t + 64];
    double s = ws[NSLOT + t] + ws[NSLOT + t + 64];
#pragma unroll
    for (int off = 32; off; off >>= 1) {
        m += __shfl_down(m, off);
        s += __shfl_down(s, off);
    }
    if (t == 0) {
        const double N = (double)NIMG * H * W;
        double mse  = m / N;
        double ssim = s / N;
        out[0] = (float)(0.8 * mse + 0.2 * (1.0 - ssim));
    }
}

extern "C" void kernel_launch(void* const* d_in, const int* in_sizes, int n_in,
                              void* d_out, int out_size, void* d_ws, size_t ws_size,
                              hipStream_t stream) {
    const float* pred = (const float*)d_in[0];
    const float* targ = (const float*)d_in[1];
    double* ws = (double*)d_ws;
    float* out = (float*)d_out;

    hybrid_init<<<1, 256, 0, stream>>>(ws);
    dim3 grid(W / TX, H / STRIP, NIMG);
    hybrid_main<<<grid, dim3(256), 0, stream>>>(pred, targ, ws);
    hybrid_fin<<<1, 64, 0, stream>>>(ws, out);
}